// Round 2
// baseline (28481.970 us; speedup 1.0000x reference)
//
#include <hip/hip_runtime.h>
#include <math.h>

#define T_LEN 4096
#define EDIM  256
#define HDIM  512
#define G4H   2048
#define NTAGS 50

__device__ __forceinline__ float sigm(float x) { return 1.0f / (1.0f + expf(-x)); }

// ---------------------------------------------------------------------------
// Kernel 1: X[d][t][perm(r)] = emb[sent[t]] @ W_ih[d]^T + b_ih[d] + b_hh[d]
// All f32. Tile: 32 t x 64 r, K chunked by 64 through LDS.
// W staged TRANSPOSED in LDS (Wk[k][r], pad 71) so compute reads are
// lane-consecutive in r (conflict-free).
// Output rows permuted so each scan-WG reads a contiguous 64-float chunk:
//   r = q*512 + g*16 + u  ->  pos = g*64 + q*16 + u
// ---------------------------------------------------------------------------
__global__ __launch_bounds__(256) void x_gemm(
    const int* __restrict__ sent, const float* __restrict__ emb,
    const float* __restrict__ Wih_f, const float* __restrict__ bih_f, const float* __restrict__ bhh_f,
    const float* __restrict__ Wih_b, const float* __restrict__ bih_b, const float* __restrict__ bhh_b,
    float* __restrict__ Xf, float* __restrict__ Xb)
{
    const int t0  = blockIdx.x * 32;
    const int r0  = blockIdx.y * 64;
    const int dir = blockIdx.z;
    const float* W  = dir ? Wih_b : Wih_f;
    const float* bi = dir ? bih_b : bih_f;
    const float* bh = dir ? bhh_b : bhh_f;
    float* X        = dir ? Xb : Xf;

    __shared__ __align__(16) float As[32][64];   // 8 KB
    __shared__ float Wk[64][71];                 // k-major, ~17.8 KB
    __shared__ int sid[32];

    const int tid = threadIdx.x;
    if (tid < 32) sid[tid] = sent[t0 + tid];
    __syncthreads();

    const int tx = tid & 31;   // r pair {tx, tx+32}
    const int ty = tid >> 5;   // t quad {ty*4 .. ty*4+3}
    float acc[4][2] = {};

    for (int kc = 0; kc < EDIM; kc += 64) {
        // Stage A tile: 32 rows x 16 float4.
        #pragma unroll
        for (int it = 0; it < 2; ++it) {
            int i = tid + it * 256;
            int tt = i >> 4, c4 = i & 15;
            float4 v = *(const float4*)(emb + (size_t)sid[tt] * EDIM + kc + c4 * 4);
            *(float4*)(&As[tt][c4 * 4]) = v;
        }
        // Stage W tile transposed: 64 rows x 16 float4 -> Wk[k][r].
        #pragma unroll
        for (int it = 0; it < 4; ++it) {
            int i = tid + it * 256;
            int rr = i >> 4, c4 = i & 15;
            float4 v = *(const float4*)(W + (size_t)(r0 + rr) * EDIM + kc + c4 * 4);
            Wk[c4 * 4 + 0][rr] = v.x;
            Wk[c4 * 4 + 1][rr] = v.y;
            Wk[c4 * 4 + 2][rr] = v.z;
            Wk[c4 * 4 + 3][rr] = v.w;
        }
        __syncthreads();

        #pragma unroll
        for (int k4 = 0; k4 < 16; ++k4) {
            float4 a[4];
            #pragma unroll
            for (int i = 0; i < 4; ++i) a[i] = *(const float4*)(&As[ty * 4 + i][k4 * 4]);
            float wA[4], wB[4];
            #pragma unroll
            for (int d = 0; d < 4; ++d) {
                wA[d] = Wk[k4 * 4 + d][tx];
                wB[d] = Wk[k4 * 4 + d][tx + 32];
            }
            #pragma unroll
            for (int i = 0; i < 4; ++i) {
                acc[i][0] += a[i].x * wA[0] + a[i].y * wA[1] + a[i].z * wA[2] + a[i].w * wA[3];
                acc[i][1] += a[i].x * wB[0] + a[i].y * wB[1] + a[i].z * wB[2] + a[i].w * wB[3];
            }
        }
        __syncthreads();
    }

    #pragma unroll
    for (int j = 0; j < 2; ++j) {
        int r = r0 + tx + 32 * j;
        float bias = bi[r] + bh[r];
        int q = r >> 9, rem = r & 511, gg = rem >> 4, uu = rem & 15;
        int pos = gg * 64 + q * 16 + uu;
        #pragma unroll
        for (int i = 0; i < 4; ++i) {
            int t = t0 + ty * 4 + i;
            X[(size_t)t * G4H + pos] = acc[i][j] + bias;
        }
    }
}

// ---------------------------------------------------------------------------
// Kernel 2: persistent bidirectional LSTM scan (f32).
// 64 WGs x 256 threads: blocks 0..31 forward, 32..63 backward.
// WG g owns hidden units [g*16, g*16+16) => 64 gate rows of W_hh held in
// VGPRs: thread (r_loc=tid&63, qc=tid>>6) holds row R cols [qc*128,+128)
// = 128 f32 registers.
// Per-step device-scope barrier: per-step counters (memset 0 per launch),
// release atomicAdd after publishing h slice; acquire spin before reading h.
// h exchanged via ping-pong f32 buffers with agent-scope atomic ld/st.
// ---------------------------------------------------------------------------
__global__ __launch_bounds__(256, 1) void lstm_scan(
    const float* __restrict__ Xf, const float* __restrict__ Xb,
    const float* __restrict__ Whh_f, const float* __restrict__ Whh_b,
    float* hbf, float* hbb,
    float* __restrict__ hsf, float* __restrict__ hsb,
    int* cntf, int* cntb)
{
    const int tid = threadIdx.x;
    const int dir = blockIdx.x >> 5;
    const int g   = blockIdx.x & 31;
    const float* X   = dir ? Xb : Xf;
    const float* Whh = dir ? Whh_b : Whh_f;
    float* hbuf = dir ? hbb : hbf;     // 2 x 512 floats, both slots zeroed
    float* hs   = dir ? hsb : hsf;
    int*   cnt  = dir ? cntb : cntf;

    const int r_loc = tid & 63;
    const int qc    = tid >> 6;
    const int R     = (r_loc >> 4) * 512 + g * 16 + (r_loc & 15);

    // This thread's 128 f32 weights into registers.
    float w[128];
    {
        const float* base = Whh + (size_t)R * HDIM + qc * 128;
        #pragma unroll
        for (int c4 = 0; c4 < 32; ++c4) {
            float4 v = *(const float4*)(base + c4 * 4);
            w[c4 * 4 + 0] = v.x; w[c4 * 4 + 1] = v.y;
            w[c4 * 4 + 2] = v.z; w[c4 * 4 + 3] = v.w;
        }
    }

    __shared__ float hl[512];
    __shared__ float pl[256];
    __shared__ float gl[64];

    float c_state = 0.0f;
    float* hin  = hbuf;        // slot 0 holds h_{-1} = 0
    float* hout = hbuf + 512;

    for (int s = 0; s < T_LEN; ++s) {
        const int t = dir ? (T_LEN - 1 - s) : s;

        // X for this step is h-independent: issue load before the barrier.
        float xv = 0.0f;
        if (tid < 64) xv = X[(size_t)t * G4H + g * 64 + tid];

        if (s > 0) {
            if (tid == 0) {
                while (__hip_atomic_load(cnt + (s - 1), __ATOMIC_ACQUIRE,
                                         __HIP_MEMORY_SCOPE_AGENT) < 32)
                    __builtin_amdgcn_s_sleep(1);
            }
            __syncthreads();
        }

        // Stage h_{t-1} into LDS (coherent loads; other WGs wrote it).
        {
            float h0 = __hip_atomic_load(hin + 2 * tid,     __ATOMIC_RELAXED, __HIP_MEMORY_SCOPE_AGENT);
            float h1 = __hip_atomic_load(hin + 2 * tid + 1, __ATOMIC_RELAXED, __HIP_MEMORY_SCOPE_AGENT);
            hl[2 * tid]     = h0;
            hl[2 * tid + 1] = h1;
        }
        __syncthreads();

        // Matvec: 128 f32 MACs/thread from register weights, h from LDS.
        float acc = 0.0f;
        const float* hbase = hl + qc * 128;
        #pragma unroll
        for (int i = 0; i < 32; ++i) {
            float4 hh = *(const float4*)(hbase + 4 * i);
            acc += w[4 * i + 0] * hh.x;
            acc += w[4 * i + 1] * hh.y;
            acc += w[4 * i + 2] * hh.z;
            acc += w[4 * i + 3] * hh.w;
        }
        pl[tid] = acc;
        __syncthreads();

        if (tid < 64)
            gl[tid] = xv + pl[tid] + pl[tid + 64] + pl[tid + 128] + pl[tid + 192];
        __syncthreads();

        if (tid < 16) {
            float iv = sigm(gl[tid]);
            float fv = sigm(gl[16 + tid]);
            float gv = tanhf(gl[32 + tid]);
            float ov = sigm(gl[48 + tid]);
            c_state = fv * c_state + iv * gv;
            float h = ov * tanhf(c_state);
            __hip_atomic_store(hout + g * 16 + tid, h, __ATOMIC_RELAXED, __HIP_MEMORY_SCOPE_AGENT);
            hs[(size_t)t * HDIM + g * 16 + tid] = h;
        }
        __threadfence();
        if (tid == 0)
            __hip_atomic_fetch_add(cnt + s, 1, __ATOMIC_RELEASE, __HIP_MEMORY_SCOPE_AGENT);

        float* tmp = hin; hin = hout; hout = tmp;
    }
}

// ---------------------------------------------------------------------------
// Kernel 3: tag_space[t] = [hs_f[t] | hs_b[t]] @ W_out^T + b_out  (f32 out)
// One block per t; wave w handles tags w, w+4, ...; shuffle-reduce per tag.
// ---------------------------------------------------------------------------
__global__ __launch_bounds__(256) void out_gemm(
    const float* __restrict__ hsf, const float* __restrict__ hsb,
    const float* __restrict__ Wout, const float* __restrict__ bout,
    float* __restrict__ out)
{
    const int t   = blockIdx.x;
    const int tid = threadIdx.x;
    __shared__ float h2[1024];

    if (tid < 128)
        *(float4*)(h2 + tid * 4) = *(const float4*)(hsf + (size_t)t * HDIM + tid * 4);
    else
        *(float4*)(h2 + 512 + (tid - 128) * 4) = *(const float4*)(hsb + (size_t)t * HDIM + (tid - 128) * 4);
    __syncthreads();

    const int wv = tid >> 6, lane = tid & 63;
    for (int tag = wv; tag < NTAGS; tag += 4) {
        const float4* wr = (const float4*)(Wout + (size_t)tag * (2 * HDIM));
        float p = 0.0f;
        #pragma unroll
        for (int c = lane; c < 256; c += 64) {
            float4 wv4 = wr[c];
            float4 hv  = *(const float4*)(h2 + c * 4);
            p += wv4.x * hv.x + wv4.y * hv.y + wv4.z * hv.z + wv4.w * hv.w;
        }
        p += __shfl_down(p, 32, 64);
        p += __shfl_down(p, 16, 64);
        p += __shfl_down(p, 8, 64);
        p += __shfl_down(p, 4, 64);
        p += __shfl_down(p, 2, 64);
        p += __shfl_down(p, 1, 64);
        if (lane == 0) out[(size_t)t * NTAGS + tag] = p + bout[tag];
    }
}

// ---------------------------------------------------------------------------
extern "C" void kernel_launch(void* const* d_in, const int* in_sizes, int n_in,
                              void* d_out, int out_size, void* d_ws, size_t ws_size,
                              hipStream_t stream)
{
    const int*   sent  = (const int*)d_in[0];
    const float* emb   = (const float*)d_in[1];
    const float* Wih_f = (const float*)d_in[2];
    const float* Whh_f = (const float*)d_in[3];
    const float* bih_f = (const float*)d_in[4];
    const float* bhh_f = (const float*)d_in[5];
    const float* Wih_b = (const float*)d_in[6];
    const float* Whh_b = (const float*)d_in[7];
    const float* bih_b = (const float*)d_in[8];
    const float* bhh_b = (const float*)d_in[9];
    const float* Wout  = (const float*)d_in[10];
    const float* bout  = (const float*)d_in[11];
    float* out = (float*)d_out;

    char* ws = (char*)d_ws;
    // Workspace layout (bytes) — identical footprint to round 1 (proven mapped):
    //   Xf   [4096*2048 f32]  @ 0          (32 MiB)
    //   Xb   [4096*2048 f32]  @ 33554432   (32 MiB)
    //   hsf  [4096*512  f32]  @ 67108864   (8 MiB)
    //   hsb  [4096*512  f32]  @ 75497472   (8 MiB)
    //   hbf  [2*512 f32]      @ 83886080
    //   hbb  [2*512 f32]      @ 83890176
    //   cntf [4096 i32]       @ 83894272
    //   cntb [4096 i32]       @ 83910656   (end 83927040)
    float* Xf   = (float*)(ws);
    float* Xb   = (float*)(ws + 33554432);
    float* hsf  = (float*)(ws + 67108864);
    float* hsb  = (float*)(ws + 75497472);
    float* hbf  = (float*)(ws + 83886080);
    float* hbb  = (float*)(ws + 83890176);
    int*   cntf = (int*)  (ws + 83894272);
    int*   cntb = (int*)  (ws + 83910656);

    // Zero h ping-pong slots + per-step barrier counters (ws is re-poisoned
    // to 0xAA before every timed launch). Graph-capture legal.
    hipMemsetAsync(ws + 83886080, 0, 40960, stream);

    dim3 gx(T_LEN / 32, G4H / 64, 2);
    x_gemm<<<gx, 256, 0, stream>>>(sent, emb, Wih_f, bih_f, bhh_f,
                                   Wih_b, bih_b, bhh_b, Xf, Xb);
    lstm_scan<<<64, 256, 0, stream>>>(Xf, Xb, Whh_f, Whh_b,
                                      hbf, hbb, hsf, hsb, cntf, cntb);
    out_gemm<<<T_LEN, 256, 0, stream>>>(hsf, hsb, Wout, bout, out);
}

// Round 3
// 11749.088 us; speedup vs baseline: 2.4242x; 2.4242x over previous
//
#include <hip/hip_runtime.h>
#include <math.h>

#define T_LEN 4096
#define EDIM  256
#define HDIM  512
#define G4H   2048
#define NTAGS 50
#define SENTW 0xFFFFFFFFu

__device__ __forceinline__ float sigm(float x) { return 1.0f / (1.0f + expf(-x)); }
__device__ __forceinline__ float u2f(unsigned u) { union { unsigned i; float f; } v; v.i = u; return v.f; }

// ---------------------------------------------------------------------------
// Kernel 1: X[d][t][perm(r)] = emb[sent[t]] @ W_ih[d]^T + b_ih[d] + b_hh[d]
// All f32. Tile: 32 t x 64 r, K chunked by 64 through LDS.
// Output rows permuted so scan-WG g reads chunk X[t*2048 + g*64 + q*16 + u]
// for gate row r = q*512 + g*16 + u.
// ---------------------------------------------------------------------------
__global__ __launch_bounds__(256) void x_gemm(
    const int* __restrict__ sent, const float* __restrict__ emb,
    const float* __restrict__ Wih_f, const float* __restrict__ bih_f, const float* __restrict__ bhh_f,
    const float* __restrict__ Wih_b, const float* __restrict__ bih_b, const float* __restrict__ bhh_b,
    float* __restrict__ Xf, float* __restrict__ Xb)
{
    const int t0  = blockIdx.x * 32;
    const int r0  = blockIdx.y * 64;
    const int dir = blockIdx.z;
    const float* W  = dir ? Wih_b : Wih_f;
    const float* bi = dir ? bih_b : bih_f;
    const float* bh = dir ? bhh_b : bhh_f;
    float* X        = dir ? Xb : Xf;

    __shared__ __align__(16) float As[32][64];
    __shared__ float Wk[64][71];
    __shared__ int sid[32];

    const int tid = threadIdx.x;
    if (tid < 32) sid[tid] = sent[t0 + tid];
    __syncthreads();

    const int tx = tid & 31;
    const int ty = tid >> 5;
    float acc[4][2] = {};

    for (int kc = 0; kc < EDIM; kc += 64) {
        #pragma unroll
        for (int it = 0; it < 2; ++it) {
            int i = tid + it * 256;
            int tt = i >> 4, c4 = i & 15;
            float4 v = *(const float4*)(emb + (size_t)sid[tt] * EDIM + kc + c4 * 4);
            *(float4*)(&As[tt][c4 * 4]) = v;
        }
        #pragma unroll
        for (int it = 0; it < 4; ++it) {
            int i = tid + it * 256;
            int rr = i >> 4, c4 = i & 15;
            float4 v = *(const float4*)(W + (size_t)(r0 + rr) * EDIM + kc + c4 * 4);
            Wk[c4 * 4 + 0][rr] = v.x;
            Wk[c4 * 4 + 1][rr] = v.y;
            Wk[c4 * 4 + 2][rr] = v.z;
            Wk[c4 * 4 + 3][rr] = v.w;
        }
        __syncthreads();

        #pragma unroll
        for (int k4 = 0; k4 < 16; ++k4) {
            float4 a[4];
            #pragma unroll
            for (int i = 0; i < 4; ++i) a[i] = *(const float4*)(&As[ty * 4 + i][k4 * 4]);
            float wA[4], wB[4];
            #pragma unroll
            for (int d = 0; d < 4; ++d) {
                wA[d] = Wk[k4 * 4 + d][tx];
                wB[d] = Wk[k4 * 4 + d][tx + 32];
            }
            #pragma unroll
            for (int i = 0; i < 4; ++i) {
                acc[i][0] += a[i].x * wA[0] + a[i].y * wA[1] + a[i].z * wA[2] + a[i].w * wA[3];
                acc[i][1] += a[i].x * wB[0] + a[i].y * wB[1] + a[i].z * wB[2] + a[i].w * wB[3];
            }
        }
        __syncthreads();
    }

    #pragma unroll
    for (int j = 0; j < 2; ++j) {
        int r = r0 + tx + 32 * j;
        float bias = bi[r] + bh[r];
        int q = r >> 9, rem = r & 511, gg = rem >> 4, uu = rem & 15;
        int pos = gg * 64 + q * 16 + uu;
        #pragma unroll
        for (int i = 0; i < 4; ++i) {
            int t = t0 + ty * 4 + i;
            X[(size_t)t * G4H + pos] = acc[i][j] + bias;
        }
    }
}

// ---------------------------------------------------------------------------
// Kernel 2: persistent bidirectional LSTM scan (f32), data-as-flag sync.
// 64 WGs x 256 threads: blocks 0..31 forward, 32..63 backward.
// WG g owns hidden units [g*16, g*16+16). Thread tid = u*16 + q*4 + qc:
//   row R = q*512 + g*16 + u, cols [qc*128, qc*128+128) in 128 registers.
// Sync: hs[t] doubles as data and flag. hs pre-memset to 0xFF (-NaN sentinel,
// unproducible). Producers: relaxed agent-scope stores. Consumers: poll own
// u64 with relaxed agent loads until both halves != sentinel. No fences, no
// cache-invalidate/writeback instructions anywhere in the loop.
// Reduction: 2x shfl_xor over qc, shfl-gather of 4 gates (same wave),
// activation + c-state on lane qc==0,q==0. Only ONE __syncthreads per step
// (hl staging); hl reuse across steps is ordered by the data-flag itself.
// ---------------------------------------------------------------------------
__global__ __launch_bounds__(256, 1) void lstm_scan(
    const float* __restrict__ Xf, const float* __restrict__ Xb,
    const float* __restrict__ Whh_f, const float* __restrict__ Whh_b,
    float* hsf, float* hsb)
{
    const int tid = threadIdx.x;
    const int dir = blockIdx.x >> 5;
    const int g   = blockIdx.x & 31;
    const float* X   = dir ? Xb : Xf;
    const float* Whh = dir ? Whh_b : Whh_f;
    float* hs = dir ? hsb : hsf;

    const int qc = tid & 3;          // column quarter
    const int q  = (tid >> 2) & 3;   // gate (i,f,g,o)
    const int u  = tid >> 4;         // unit within WG slice
    const int R  = q * 512 + g * 16 + u;

    float w[128];
    {
        const float* base = Whh + (size_t)R * HDIM + qc * 128;
        #pragma unroll
        for (int c4 = 0; c4 < 32; ++c4) {
            float4 v = *(const float4*)(base + c4 * 4);
            w[c4 * 4 + 0] = v.x; w[c4 * 4 + 1] = v.y;
            w[c4 * 4 + 2] = v.z; w[c4 * 4 + 3] = v.w;
        }
    }

    __shared__ float hl[512];

    const bool is_x   = (qc == 0);
    const bool is_act = (qc == 0) && (q == 0);
    const int  xoff   = g * 64 + q * 16 + u;

    float c_state = 0.0f;
    float xv = 0.0f;
    {
        int t0 = dir ? (T_LEN - 1) : 0;
        if (is_x) xv = X[(size_t)t0 * G4H + xoff];
    }

    for (int s = 0; s < T_LEN; ++s) {
        const int t = dir ? (T_LEN - 1 - s) : s;

        // Software-pipeline next step's x (h-independent).
        float xv_n = 0.0f;
        if (s + 1 < T_LEN) {
            int tn = dir ? (T_LEN - 2 - s) : (s + 1);
            if (is_x) xv_n = X[(size_t)tn * G4H + xoff];
        }

        if (s == 0) {
            hl[2 * tid] = 0.0f;
            hl[2 * tid + 1] = 0.0f;
        } else {
            const int tp = dir ? (t + 1) : (t - 1);
            const unsigned long long* p =
                (const unsigned long long*)(hs + (size_t)tp * HDIM) + tid;
            unsigned long long v;
            do {
                v = __hip_atomic_load(p, __ATOMIC_RELAXED, __HIP_MEMORY_SCOPE_AGENT);
            } while (((unsigned)v == SENTW) || ((unsigned)(v >> 32) == SENTW));
            hl[2 * tid]     = u2f((unsigned)v);
            hl[2 * tid + 1] = u2f((unsigned)(v >> 32));
        }
        __syncthreads();

        // Matvec: 128 f32 MACs/thread; same-address LDS reads broadcast.
        float acc = 0.0f;
        const float* hbase = hl + qc * 128;
        #pragma unroll
        for (int i = 0; i < 32; ++i) {
            float4 hh = *(const float4*)(hbase + 4 * i);
            acc += w[4 * i + 0] * hh.x;
            acc += w[4 * i + 1] * hh.y;
            acc += w[4 * i + 2] * hh.z;
            acc += w[4 * i + 3] * hh.w;
        }
        // Reduce across qc (lane bits 0..1).
        acc += __shfl_xor(acc, 1, 64);
        acc += __shfl_xor(acc, 2, 64);
        if (is_x) acc += xv;   // full row value now on qc==0 lanes

        // Gather 4 gates of this unit (lanes lbase+{0,4,8,12}, same wave).
        int lbase = (tid & 63) & ~15;
        float gi = __shfl(acc, lbase + 0, 64);
        float gf = __shfl(acc, lbase + 4, 64);
        float gg = __shfl(acc, lbase + 8, 64);
        float go = __shfl(acc, lbase + 12, 64);

        if (is_act) {
            float iv = sigm(gi), fv = sigm(gf);
            float gv = tanhf(gg), ov = sigm(go);
            c_state = fv * c_state + iv * gv;
            float h = ov * tanhf(c_state);
            __hip_atomic_store(hs + (size_t)t * HDIM + g * 16 + u, h,
                               __ATOMIC_RELAXED, __HIP_MEMORY_SCOPE_AGENT);
        }
        xv = xv_n;
        // No trailing sync needed: next-step hl writes are gated by the
        // data-flag poll, which can only succeed after every wave here has
        // finished its matvec reads and published h.
    }
}

// ---------------------------------------------------------------------------
// Kernel 3: tag_space[t] = [hs_f[t] | hs_b[t]] @ W_out^T + b_out  (f32 out)
// ---------------------------------------------------------------------------
__global__ __launch_bounds__(256) void out_gemm(
    const float* __restrict__ hsf, const float* __restrict__ hsb,
    const float* __restrict__ Wout, const float* __restrict__ bout,
    float* __restrict__ out)
{
    const int t   = blockIdx.x;
    const int tid = threadIdx.x;
    __shared__ float h2[1024];

    if (tid < 128)
        *(float4*)(h2 + tid * 4) = *(const float4*)(hsf + (size_t)t * HDIM + tid * 4);
    else
        *(float4*)(h2 + 512 + (tid - 128) * 4) = *(const float4*)(hsb + (size_t)t * HDIM + (tid - 128) * 4);
    __syncthreads();

    const int wv = tid >> 6, lane = tid & 63;
    for (int tag = wv; tag < NTAGS; tag += 4) {
        const float4* wr = (const float4*)(Wout + (size_t)tag * (2 * HDIM));
        float p = 0.0f;
        #pragma unroll
        for (int c = lane; c < 256; c += 64) {
            float4 wv4 = wr[c];
            float4 hv  = *(const float4*)(h2 + c * 4);
            p += wv4.x * hv.x + wv4.y * hv.y + wv4.z * hv.z + wv4.w * hv.w;
        }
        p += __shfl_down(p, 32, 64);
        p += __shfl_down(p, 16, 64);
        p += __shfl_down(p, 8, 64);
        p += __shfl_down(p, 4, 64);
        p += __shfl_down(p, 2, 64);
        p += __shfl_down(p, 1, 64);
        if (lane == 0) out[(size_t)t * NTAGS + tag] = p + bout[tag];
    }
}

// ---------------------------------------------------------------------------
extern "C" void kernel_launch(void* const* d_in, const int* in_sizes, int n_in,
                              void* d_out, int out_size, void* d_ws, size_t ws_size,
                              hipStream_t stream)
{
    const int*   sent  = (const int*)d_in[0];
    const float* emb   = (const float*)d_in[1];
    const float* Wih_f = (const float*)d_in[2];
    const float* Whh_f = (const float*)d_in[3];
    const float* bih_f = (const float*)d_in[4];
    const float* bhh_f = (const float*)d_in[5];
    const float* Wih_b = (const float*)d_in[6];
    const float* Whh_b = (const float*)d_in[7];
    const float* bih_b = (const float*)d_in[8];
    const float* bhh_b = (const float*)d_in[9];
    const float* Wout  = (const float*)d_in[10];
    const float* bout  = (const float*)d_in[11];
    float* out = (float*)d_out;

    char* ws = (char*)d_ws;
    // Workspace layout (bytes):
    //   Xf  [4096*2048 f32] @ 0         (32 MiB)
    //   Xb  [4096*2048 f32] @ 33554432  (32 MiB)
    //   hsf [4096*512  f32] @ 67108864  (8 MiB)   also the sync flags
    //   hsb [4096*512  f32] @ 75497472  (8 MiB)   also the sync flags
    float* Xf  = (float*)(ws);
    float* Xb  = (float*)(ws + 33554432);
    float* hsf = (float*)(ws + 67108864);
    float* hsb = (float*)(ws + 75497472);

    // Sentinel-fill hs (0xFFFFFFFF = -NaN, never produced by o*tanh(c)).
    // Graph-capture legal; ~16 MiB memset ≈ 3 µs, stream-ordered before scan.
    hipMemsetAsync(ws + 67108864, 0xFF, 16777216, stream);

    dim3 gx(T_LEN / 32, G4H / 64, 2);
    x_gemm<<<gx, 256, 0, stream>>>(sent, emb, Wih_f, bih_f, bhh_f,
                                   Wih_b, bih_b, bhh_b, Xf, Xb);
    lstm_scan<<<64, 256, 0, stream>>>(Xf, Xb, Whh_f, Whh_b, hsf, hsb);
    out_gemm<<<T_LEN, 256, 0, stream>>>(hsf, hsb, Wout, bout, out);
}

// Round 4
// 9063.943 us; speedup vs baseline: 3.1423x; 1.2962x over previous
//
#include <hip/hip_runtime.h>
#include <math.h>

#define T_LEN 4096
#define EDIM  256
#define HDIM  512
#define NTAGS 50
#define SENTW 0xFFFFFFFFu

__device__ __forceinline__ float sigm(float x) { return 1.0f / (1.0f + expf(-x)); }
__device__ __forceinline__ float u2f(unsigned u) { union { unsigned i; float f; } v; v.i = u; return v.f; }
__device__ __forceinline__ float rdlane(float v, int l) {
    union { float f; int i; } a, r;
    a.f = v;
    r.i = __builtin_amdgcn_readlane(a.i, l);   // SGPR broadcast, VALU-only
    return r.f;
}

// ---------------------------------------------------------------------------
// Persistent bidirectional LSTM scan (f32), data-as-flag sync, SGPR-broadcast
// matvec, on-the-fly x = W_ih·emb[sent[t]] (no X buffer, no x_gemm kernel).
//
// 64 WGs x 256 threads: blocks 0..31 forward, 32..63 backward.
// WG g owns hidden units [g*16,+16) => 64 gate rows. lane = row:
//   q = lane>>4 (gate i,f,g,o), u = lane&15, R = q*512 + g*16 + u.
// Wave wv owns column block: W_hh cols [wv*128,+128) (128 VGPRs) and
// W_ih cols [wv*64,+64) (64 VGPRs).
// Sync: hs[t] doubles as data+flag (pre-memset 0xFF = -NaN, unproducible by
// o*tanh(c)). Producers: relaxed agent stores. Each wave polls only its own
// 128-float segment of h_{t-1} (64 u64 words, 1/lane), then broadcasts via
// v_readlane + v_fmac — zero LDS in the matvec, no pre-matvec barrier.
// Reduction: partials in pl[2][256] (parity double-buffer), ONE barrier per
// step, wave 0 finalizes (gather gates via shfl, activations on 16 lanes,
// one coalesced 64B h store).
// Race-freedom of pl: wave w writes pl[(s)&1] only after passing barrier(s-1)
// wait no—after barrier(s) ... wave w writes pl[s&1] before barrier(s); wave 0
// reads pl[s&1] after barrier(s) and before its barrier(s+1) arrival; any
// other wave can only rewrite pl[s&1] at step s+2, after passing barrier(s+1),
// which requires wave 0 to have arrived there — i.e. after wave 0's read. QED.
// ---------------------------------------------------------------------------
__global__ __launch_bounds__(256, 1) void lstm_scan(
    const int* __restrict__ sent, const float* __restrict__ emb,
    const float* __restrict__ Wih_f, const float* __restrict__ Whh_f,
    const float* __restrict__ bih_f, const float* __restrict__ bhh_f,
    const float* __restrict__ Wih_b, const float* __restrict__ Whh_b,
    const float* __restrict__ bih_b, const float* __restrict__ bhh_b,
    float* hsf, float* hsb)
{
    const int tid  = threadIdx.x;
    const int lane = tid & 63;
    const int wv   = tid >> 6;          // wave id = column block
    const int dir  = blockIdx.x >> 5;
    const int g    = blockIdx.x & 31;

    const float* Wih = dir ? Wih_b : Wih_f;
    const float* Whh = dir ? Whh_b : Whh_f;
    const float* bih = dir ? bih_b : bih_f;
    const float* bhh = dir ? bhh_b : bhh_f;
    float* hs = dir ? hsb : hsf;

    const int q = lane >> 4;
    const int u = lane & 15;
    const int R = q * 512 + g * 16 + u;

    // W_hh cols [wv*128,+128) of row R -> 128 VGPRs.
    float wh[128];
    {
        const float* base = Whh + (size_t)R * HDIM + wv * 128;
        #pragma unroll
        for (int i = 0; i < 32; ++i) {
            float4 v = *(const float4*)(base + 4 * i);
            wh[4*i] = v.x; wh[4*i+1] = v.y; wh[4*i+2] = v.z; wh[4*i+3] = v.w;
        }
    }
    // W_ih cols [wv*64,+64) of row R -> 64 VGPRs.
    float wx[64];
    {
        const float* base = Wih + (size_t)R * EDIM + wv * 64;
        #pragma unroll
        for (int i = 0; i < 16; ++i) {
            float4 v = *(const float4*)(base + 4 * i);
            wx[4*i] = v.x; wx[4*i+1] = v.y; wx[4*i+2] = v.z; wx[4*i+3] = v.w;
        }
    }
    const float bias = bih[R] + bhh[R];

    __shared__ float pl[2][256];

    float c_state = 0.0f;

    // Embedding value pipeline: lane holds emb[sent[t]][wv*64 + lane].
    float ecur;
    {
        int t0 = dir ? (T_LEN - 1) : 0;
        ecur = emb[(size_t)sent[t0] * EDIM + wv * 64 + lane];
    }

    for (int s = 0; s < T_LEN; ++s) {
        const int t = dir ? (T_LEN - 1 - s) : s;

        // Issue first poll sample ASAP so it flies under the x-matvec.
        const unsigned long long* p = nullptr;
        unsigned long long v = 0;
        if (s > 0) {
            const int tp = dir ? (t + 1) : (t - 1);
            p = (const unsigned long long*)(hs + (size_t)tp * HDIM + wv * 128) + lane;
            v = __hip_atomic_load(p, __ATOMIC_RELAXED, __HIP_MEMORY_SCOPE_AGENT);
        }
        // Prefetch next step's embedding value (h-independent).
        float enext = 0.0f;
        if (s + 1 < T_LEN) {
            int tn = dir ? (t - 1) : (t + 1);
            enext = emb[(size_t)sent[tn] * EDIM + wv * 64 + lane];
        }

        // x partial: 64 SGPR-broadcast MACs (overlaps in-flight poll load).
        float acc = 0.0f;
        #pragma unroll
        for (int i = 0; i < 64; ++i)
            acc = fmaf(wx[i], rdlane(ecur, i), acc);

        if (s > 0) {
            while (((unsigned)v == SENTW) || ((unsigned)(v >> 32) == SENTW))
                v = __hip_atomic_load(p, __ATOMIC_RELAXED, __HIP_MEMORY_SCOPE_AGENT);
            float h0 = u2f((unsigned)v);
            float h1 = u2f((unsigned)(v >> 32));
            // h partial: 128 SGPR-broadcast MACs, zero LDS traffic.
            #pragma unroll
            for (int i = 0; i < 64; ++i) {
                acc = fmaf(wh[2*i],     rdlane(h0, i), acc);
                acc = fmaf(wh[2*i + 1], rdlane(h1, i), acc);
            }
        }

        pl[s & 1][wv * 64 + lane] = acc;
        __syncthreads();

        if (wv == 0) {
            const float* pb = pl[s & 1];
            float tot = pb[lane] + pb[64 + lane] + pb[128 + lane] + pb[192 + lane] + bias;
            float gi = __shfl(tot, u,      64);
            float gf = __shfl(tot, u + 16, 64);
            float gg = __shfl(tot, u + 32, 64);
            float go = __shfl(tot, u + 48, 64);
            if (lane < 16) {
                float iv = sigm(gi), fv = sigm(gf);
                float gv = tanhf(gg), ov = sigm(go);
                c_state = fv * c_state + iv * gv;
                float h = ov * tanhf(c_state);
                __hip_atomic_store(hs + (size_t)t * HDIM + g * 16 + u, h,
                                   __ATOMIC_RELAXED, __HIP_MEMORY_SCOPE_AGENT);
            }
        }
        ecur = enext;
    }
}

// ---------------------------------------------------------------------------
// tag_space[t] = [hs_f[t] | hs_b[t]] @ W_out^T + b_out  (f32 out)
// ---------------------------------------------------------------------------
__global__ __launch_bounds__(256) void out_gemm(
    const float* __restrict__ hsf, const float* __restrict__ hsb,
    const float* __restrict__ Wout, const float* __restrict__ bout,
    float* __restrict__ out)
{
    const int t   = blockIdx.x;
    const int tid = threadIdx.x;
    __shared__ float h2[1024];

    if (tid < 128)
        *(float4*)(h2 + tid * 4) = *(const float4*)(hsf + (size_t)t * HDIM + tid * 4);
    else
        *(float4*)(h2 + 512 + (tid - 128) * 4) = *(const float4*)(hsb + (size_t)t * HDIM + (tid - 128) * 4);
    __syncthreads();

    const int wv = tid >> 6, lane = tid & 63;
    for (int tag = wv; tag < NTAGS; tag += 4) {
        const float4* wr = (const float4*)(Wout + (size_t)tag * (2 * HDIM));
        float p = 0.0f;
        #pragma unroll
        for (int c = lane; c < 256; c += 64) {
            float4 wv4 = wr[c];
            float4 hv  = *(const float4*)(h2 + c * 4);
            p += wv4.x * hv.x + wv4.y * hv.y + wv4.z * hv.z + wv4.w * hv.w;
        }
        p += __shfl_down(p, 32, 64);
        p += __shfl_down(p, 16, 64);
        p += __shfl_down(p, 8, 64);
        p += __shfl_down(p, 4, 64);
        p += __shfl_down(p, 2, 64);
        p += __shfl_down(p, 1, 64);
        if (lane == 0) out[(size_t)t * NTAGS + tag] = p + bout[tag];
    }
}

// ---------------------------------------------------------------------------
extern "C" void kernel_launch(void* const* d_in, const int* in_sizes, int n_in,
                              void* d_out, int out_size, void* d_ws, size_t ws_size,
                              hipStream_t stream)
{
    const int*   sent  = (const int*)d_in[0];
    const float* emb   = (const float*)d_in[1];
    const float* Wih_f = (const float*)d_in[2];
    const float* Whh_f = (const float*)d_in[3];
    const float* bih_f = (const float*)d_in[4];
    const float* bhh_f = (const float*)d_in[5];
    const float* Wih_b = (const float*)d_in[6];
    const float* Whh_b = (const float*)d_in[7];
    const float* bih_b = (const float*)d_in[8];
    const float* bhh_b = (const float*)d_in[9];
    const float* Wout  = (const float*)d_in[10];
    const float* bout  = (const float*)d_in[11];
    float* out = (float*)d_out;

    char* ws = (char*)d_ws;
    // Workspace: hsf [4096*512 f32] @ 0 (8 MiB), hsb @ 8 MiB. Both double as
    // sync flags: sentinel-fill with 0xFF (-NaN, never produced by o*tanh(c)).
    float* hsf = (float*)(ws);
    float* hsb = (float*)(ws + 8388608);
    hipMemsetAsync(ws, 0xFF, 16777216, stream);

    lstm_scan<<<64, 256, 0, stream>>>(sent, emb,
                                      Wih_f, Whh_f, bih_f, bhh_f,
                                      Wih_b, Whh_b, bih_b, bhh_b,
                                      hsf, hsb);
    out_gemm<<<T_LEN, 256, 0, stream>>>(hsf, hsb, Wout, bout, out);
}